// Round 1
// baseline (293.198 us; speedup 1.0000x reference)
//
#include <hip/hip_runtime.h>
#include <stdint.h>

typedef unsigned short u16;
typedef __attribute__((ext_vector_type(8))) short short8;   // 8 bf16 = 4 VGPRs (MFMA A/B frag)
typedef __attribute__((ext_vector_type(4))) short short4v;
typedef __attribute__((ext_vector_type(4))) float float4v;  // MFMA C/D frag

#define NB 2
#define NT 2048
#define NC 1024
#define NH 16
#define ND 64
#define NM (NB*NT)   // 4096 rows total

// fp32 -> bf16 round-to-nearest-even
__device__ __forceinline__ u16 f2bf(float f) {
  union { float f; uint32_t u; } v; v.f = f;
  uint32_t u = v.u;
  u += 0x7fffu + ((u >> 16) & 1u);
  return (u16)(u >> 16);
}

// async global->LDS, 16B per lane; lds dest must be wave-uniform (lane i -> lds + i*16B)
__device__ __forceinline__ void gld_lds16(const u16* g, u16* lds) {
  __builtin_amdgcn_global_load_lds(
      (const __attribute__((address_space(1))) uint32_t*)g,
      (__attribute__((address_space(3))) uint32_t*)lds,
      16, 0, 0);
}

// ---------------- cast: x, Wk, Wq, Wv, Wp -> bf16 ----------------
__global__ __launch_bounds__(256) void cast_all(
    const float* __restrict__ x,  const float* __restrict__ wk,
    const float* __restrict__ wq, const float* __restrict__ wv,
    const float* __restrict__ wp,
    u16* __restrict__ xb, u16* __restrict__ wkb, u16* __restrict__ wqb,
    u16* __restrict__ wvb, u16* __restrict__ wpb) {
  const int NX = NM * NC / 4;   // 1048576 float4s
  const int NW = NC * NC / 4;   // 262144 float4s
  int i = blockIdx.x * 256 + threadIdx.x;
  const float* src; u16* dst; int off;
  if (i < NX)            { src = x;  dst = xb;  off = i; }
  else if (i < NX+NW)    { src = wk; dst = wkb; off = i - NX; }
  else if (i < NX+2*NW)  { src = wq; dst = wqb; off = i - NX - NW; }
  else if (i < NX+3*NW)  { src = wv; dst = wvb; off = i - NX - 2*NW; }
  else if (i < NX+4*NW)  { src = wp; dst = wpb; off = i - NX - 3*NW; }
  else return;
  float4v f = ((const float4v*)src)[off];
  short4v o;
  o.x = (short)f2bf(f.x); o.y = (short)f2bf(f.y);
  o.z = (short)f2bf(f.z); o.w = (short)f2bf(f.w);
  ((short4v*)dst)[off] = o;
}

// ---------------- shared 128x128xK GEMM core: C = A * W^T ----------------
// A: [.., 1024] bf16 row-major (tile base passed), W: [.., 1024] bf16 row-major.
// LDS tiles [128 rows][64 k] with 16B-chunk XOR swizzle (chunk ^= row&7).
__device__ __forceinline__ void gemm_tile(
    const u16* __restrict__ A_tile, const u16* __restrict__ W_tile,
    u16* As, u16* Bs, float4v (&acc)[4][4]) {
  const int tid  = threadIdx.x;
  const int wave = tid >> 6, lane = tid & 63;
  const int quad = lane >> 4, l15 = lane & 15;
  const int wm = wave >> 1, wn = wave & 1;
  const int c8 = lane & 7, r8 = lane >> 3;

#pragma unroll
  for (int i = 0; i < 4; i++)
#pragma unroll
    for (int j = 0; j < 4; j++) acc[i][j] = (float4v){0.f, 0.f, 0.f, 0.f};

  for (int k0 = 0; k0 < NC; k0 += 64) {
    // stage: each wave stages 32 rows of A and 32 rows of B (4 instrs each)
#pragma unroll
    for (int i = 0; i < 4; i++) {
      int row = wave * 32 + i * 8 + r8;
      int gc  = c8 ^ (row & 7);
      gld_lds16(A_tile + row * NC + k0 + gc * 8, As + (wave * 32 + i * 8) * 64);
      gld_lds16(W_tile + row * NC + k0 + gc * 8, Bs + (wave * 32 + i * 8) * 64);
    }
    __syncthreads();
#pragma unroll
    for (int kk = 0; kk < 2; kk++) {
      short8 af[4], bf[4];
#pragma unroll
      for (int mt = 0; mt < 4; mt++) {
        int row = wm * 64 + mt * 16 + l15;
        int ch  = (kk * 4 + quad) ^ (row & 7);
        af[mt] = *(const short8*)(As + row * 64 + ch * 8);
      }
#pragma unroll
      for (int nt = 0; nt < 4; nt++) {
        int row = wn * 64 + nt * 16 + l15;
        int ch  = (kk * 4 + quad) ^ (row & 7);
        bf[nt] = *(const short8*)(Bs + row * 64 + ch * 8);
      }
#pragma unroll
      for (int mt = 0; mt < 4; mt++)
#pragma unroll
        for (int nt = 0; nt < 4; nt++)
          acc[mt][nt] = __builtin_amdgcn_mfma_f32_16x16x32_bf16(af[mt], bf[nt], acc[mt][nt], 0, 0, 0);
    }
    __syncthreads();
  }
}

// ---------------- fused QKV projection ----------------
// grid.x: 24 (0-7 -> Q, 8-15 -> K, 16-23 -> V), grid.y: 32 (m tiles)
__global__ __launch_bounds__(256) void qkv_gemm(
    const u16* __restrict__ xb,
    const u16* __restrict__ wqb, const u16* __restrict__ wkb, const u16* __restrict__ wvb,
    const float* __restrict__ bq, const float* __restrict__ bk, const float* __restrict__ bv,
    u16* __restrict__ Q, u16* __restrict__ K, u16* __restrict__ Vt) {
  __shared__ u16 As[128 * 64];
  __shared__ u16 Bs[128 * 64];
  const int nb  = blockIdx.x;
  const int mat = nb >> 3;            // 0=Q 1=K 2=V
  const int n0  = (nb & 7) * 128;     // col base within matrix
  const int m0  = blockIdx.y * 128;
  const u16*   W    = (mat == 0) ? wqb : (mat == 1) ? wkb : wvb;
  const float* bias = (mat == 0) ? bq  : (mat == 1) ? bk  : bv;

  float4v acc[4][4];
  gemm_tile(xb + m0 * NC, W + n0 * NC, As, Bs, acc);

  const int tid = threadIdx.x, wave = tid >> 6, lane = tid & 63;
  const int quad = lane >> 4, l15 = lane & 15;
  const int wm = wave >> 1, wn = wave & 1;
#pragma unroll
  for (int nt = 0; nt < 4; nt++) {
    int col = n0 + wn * 64 + nt * 16 + l15;
    float bval = bias[col];
#pragma unroll
    for (int mt = 0; mt < 4; mt++) {
      int rowb = m0 + wm * 64 + mt * 16 + quad * 4;
#pragma unroll
      for (int r = 0; r < 4; r++) {
        float vv = acc[mt][nt][r] + bval;
        int gm = rowb + r;
        if (mat == 2) {
          int b = gm >> 11, t = gm & 2047;
          int h = col >> 6, d = col & 63;
          Vt[((b * NH + h) * ND + d) * NT + t] = f2bf(vv);   // V transposed: [B,H,D,T]
        } else {
          u16* dst = (mat == 0) ? Q : K;
          dst[gm * NC + col] = f2bf(vv);
        }
      }
    }
  }
}

// ---------------- output projection: out = O * Wp^T + bp (fp32 out) ----------------
__global__ __launch_bounds__(256) void out_gemm(
    const u16* __restrict__ Ob, const u16* __restrict__ wpb,
    const float* __restrict__ bp, float* __restrict__ out) {
  __shared__ u16 As[128 * 64];
  __shared__ u16 Bs[128 * 64];
  const int n0 = blockIdx.x * 128;
  const int m0 = blockIdx.y * 128;
  float4v acc[4][4];
  gemm_tile(Ob + m0 * NC, wpb + n0 * NC, As, Bs, acc);

  const int tid = threadIdx.x, wave = tid >> 6, lane = tid & 63;
  const int quad = lane >> 4, l15 = lane & 15;
  const int wm = wave >> 1, wn = wave & 1;
#pragma unroll
  for (int nt = 0; nt < 4; nt++) {
    int col = n0 + wn * 64 + nt * 16 + l15;
    float bval = bp[col];
#pragma unroll
    for (int mt = 0; mt < 4; mt++) {
      int rowb = m0 + wm * 64 + mt * 16 + quad * 4;
#pragma unroll
      for (int r = 0; r < 4; r++)
        out[(rowb + r) * NC + col] = acc[mt][nt][r] + bval;
    }
  }
}

// ---------------- flash attention (causal) ----------------
// grid: (T/64, B*H). block 256 = 4 waves, each wave owns 16 q rows.
// Q,K: [B*T, C] bf16 (head-strided). Vt: [B,H,D,T] bf16. O: [B*T, C] bf16.
__global__ __launch_bounds__(256) void attn(
    const u16* __restrict__ Q, const u16* __restrict__ K,
    const u16* __restrict__ Vt, u16* __restrict__ O) {
  __shared__ u16 Kc[64 * 64];       // [s][d], 128B rows, swizzled
  __shared__ u16 Vc[64 * 64];       // [d][s] (V^T), 128B rows, swizzled
  __shared__ u16 Pl[4][16 * 64];    // per-wave P [16 q][64 s], swizzled

  const int tid = threadIdx.x, wave = tid >> 6, lane = tid & 63;
  const int quad = lane >> 4, l15 = lane & 15;
  const int c8 = lane & 7, r8 = lane >> 3;
  const int bh = blockIdx.y, b = bh >> 4, h = bh & 15;
  const int qb_block = blockIdx.x * 64;
  const int qbase = qb_block + wave * 16;
  const float scale = 0.125f;  // 1/sqrt(64)

  // Q fragments (A-operand layout): lane holds q[qbase+l15][kk*32 + quad*8 + j]
  short8 qf[2];
  {
    const u16* qrow = Q + (size_t)(b * NT + qbase + l15) * NC + h * ND + quad * 8;
    qf[0] = *(const short8*)(qrow);
    qf[1] = *(const short8*)(qrow + 32);
  }

  float m_r[4], l_r[4];
  float4v o_acc[4];
#pragma unroll
  for (int r = 0; r < 4; r++) { m_r[r] = -1e30f; l_r[r] = 0.f; }
#pragma unroll
  for (int dt = 0; dt < 4; dt++) o_acc[dt] = (float4v){0.f, 0.f, 0.f, 0.f};

  for (int s0 = 0; s0 <= qb_block; s0 += 64) {
    // stage K chunk [64 s][64 d] and V^T chunk [64 d][64 s]
#pragma unroll
    for (int i = 0; i < 2; i++) {
      int row = wave * 16 + i * 8 + r8;
      int gc  = c8 ^ (row & 7);
      gld_lds16(K  + (size_t)(b * NT + s0 + row) * NC + h * ND + gc * 8,
                Kc + (wave * 16 + i * 8) * 64);
      gld_lds16(Vt + (size_t)(bh * ND + row) * NT + s0 + gc * 8,
                Vc + (wave * 16 + i * 8) * 64);
    }
    __syncthreads();

    // S = Q K^T  (4 subtiles of 16 s)
    float4v sa[4];
#pragma unroll
    for (int sub = 0; sub < 4; sub++) {
      float4v a = (float4v){0.f, 0.f, 0.f, 0.f};
#pragma unroll
      for (int kk = 0; kk < 2; kk++) {
        int row = sub * 16 + l15;
        int ch  = (kk * 4 + quad) ^ (row & 7);
        short8 kf = *(const short8*)(Kc + row * 64 + ch * 8);
        a = __builtin_amdgcn_mfma_f32_16x16x32_bf16(qf[kk], kf, a, 0, 0, 0);
      }
      sa[sub] = a;
    }

    // scale + causal mask (only the diagonal chunk needs it)
    float sv[4][4];
    const bool mask_iter = (s0 + 64 > qb_block);
#pragma unroll
    for (int sub = 0; sub < 4; sub++)
#pragma unroll
      for (int r = 0; r < 4; r++) {
        float v = sa[sub][r] * scale;
        if (mask_iter) {
          int sg = s0 + sub * 16 + l15;
          int qg = qbase + quad * 4 + r;
          if (sg > qg) v = -1e30f;
        }
        sv[sub][r] = v;
      }

    // online softmax: row max over 64 cols (16 lanes of the quad hold them)
    float mx[4];
#pragma unroll
    for (int r = 0; r < 4; r++)
      mx[r] = fmaxf(fmaxf(sv[0][r], sv[1][r]), fmaxf(sv[2][r], sv[3][r]));
#pragma unroll
    for (int msk = 1; msk < 16; msk <<= 1)
#pragma unroll
      for (int r = 0; r < 4; r++)
        mx[r] = fmaxf(mx[r], __shfl_xor(mx[r], msk));

    float mnew[4], alpha[4], rs[4];
#pragma unroll
    for (int r = 0; r < 4; r++) {
      mnew[r]  = fmaxf(m_r[r], mx[r]);
      alpha[r] = __expf(m_r[r] - mnew[r]);
      rs[r]    = 0.f;
    }

    // P = exp(S - mnew); write bf16 to swizzled LDS (C-layout -> memory)
#pragma unroll
    for (int sub = 0; sub < 4; sub++)
#pragma unroll
      for (int r = 0; r < 4; r++) {
        float p = __expf(sv[sub][r] - mnew[r]);
        rs[r] += p;
        int row  = quad * 4 + r;
        int colb = sub * 16 + l15;
        int ch   = (colb >> 3) ^ (row & 7);
        Pl[wave][row * 64 + ch * 8 + (colb & 7)] = f2bf(p);
      }
#pragma unroll
    for (int msk = 1; msk < 16; msk <<= 1)
#pragma unroll
      for (int r = 0; r < 4; r++)
        rs[r] += __shfl_xor(rs[r], msk);
#pragma unroll
    for (int r = 0; r < 4; r++) {
      l_r[r] = l_r[r] * alpha[r] + rs[r];
      m_r[r] = mnew[r];
    }

    asm volatile("s_waitcnt lgkmcnt(0)" ::: "memory");  // P writes visible to own wave

    // O *= alpha, then O += P * V
#pragma unroll
    for (int dt = 0; dt < 4; dt++)
#pragma unroll
      for (int r = 0; r < 4; r++)
        o_acc[dt][r] *= alpha[r];
#pragma unroll
    for (int half = 0; half < 2; half++) {
      int chp = (half * 4 + quad) ^ (l15 & 7);
      short8 pf = *(const short8*)(Pl[wave] + l15 * 64 + chp * 8);
#pragma unroll
      for (int dt = 0; dt < 4; dt++) {
        int row = dt * 16 + l15;
        int ch  = (half * 4 + quad) ^ (row & 7);
        short8 vf = *(const short8*)(Vc + row * 64 + ch * 8);
        o_acc[dt] = __builtin_amdgcn_mfma_f32_16x16x32_bf16(pf, vf, o_acc[dt], 0, 0, 0);
      }
    }
    __syncthreads();
  }

  // epilogue: O / l  -> bf16 [B*T, C]
#pragma unroll
  for (int dt = 0; dt < 4; dt++)
#pragma unroll
    for (int r = 0; r < 4; r++) {
      int qg = qbase + quad * 4 + r;
      int d  = dt * 16 + l15;
      float v = o_acc[dt][r] / l_r[r];
      O[(size_t)(b * NT + qg) * NC + h * ND + d] = f2bf(v);
    }
}

extern "C" void kernel_launch(void* const* d_in, const int* in_sizes, int n_in,
                              void* d_out, int out_size, void* d_ws, size_t ws_size,
                              hipStream_t stream) {
  // setup_inputs order: x, Wk, bk, Wq, bq, Wv, bv, Wp, bp
  const float* x  = (const float*)d_in[0];
  const float* Wk = (const float*)d_in[1];
  const float* bk = (const float*)d_in[2];
  const float* Wq = (const float*)d_in[3];
  const float* bq = (const float*)d_in[4];
  const float* Wv = (const float*)d_in[5];
  const float* bv = (const float*)d_in[6];
  const float* Wp = (const float*)d_in[7];
  const float* bp = (const float*)d_in[8];
  float* out = (float*)d_out;

  uint8_t* ws = (uint8_t*)d_ws;
  const size_t MB = 1u << 20;
  u16* xb  = (u16*)(ws + 0 * MB);    // 8 MB
  u16* wkb = (u16*)(ws + 8 * MB);    // 2 MB
  u16* wqb = (u16*)(ws + 10 * MB);
  u16* wvb = (u16*)(ws + 12 * MB);
  u16* wpb = (u16*)(ws + 14 * MB);
  u16* Qb  = (u16*)(ws + 16 * MB);   // 8 MB
  u16* Kb  = (u16*)(ws + 24 * MB);   // 8 MB
  u16* Vtb = (u16*)(ws + 32 * MB);   // 8 MB  [B,H,D,T]
  u16* Ob  = (u16*)(ws + 40 * MB);   // 8 MB

  cast_all<<<8192, 256, 0, stream>>>(x, Wk, Wq, Wv, Wp, xb, wkb, wqb, wvb, wpb);
  qkv_gemm<<<dim3(24, 32), 256, 0, stream>>>(xb, wqb, wkb, wvb, bq, bk, bv, Qb, Kb, Vtb);
  attn<<<dim3(32, 32), 256, 0, stream>>>(Qb, Kb, Vtb, Ob);
  out_gemm<<<dim3(8, 32), 256, 0, stream>>>(Ob, wpb, bp, out);
}

// Round 2
// 253.513 us; speedup vs baseline: 1.1565x; 1.1565x over previous
//
#include <hip/hip_runtime.h>
#include <stdint.h>

typedef unsigned short u16;
typedef __attribute__((ext_vector_type(8))) short short8;   // 8 bf16 = 4 VGPRs (MFMA A/B frag)
typedef __attribute__((ext_vector_type(4))) short short4v;
typedef __attribute__((ext_vector_type(4))) float float4v;  // MFMA C/D frag

#define NB 2
#define NT 2048
#define NC 1024
#define NH 16
#define ND 64
#define NM (NB*NT)   // 4096 rows total

// fine-grained barriers: never drain the prefetch queue (vmcnt(4) leaves the
// 4 just-issued next-chunk global_load_lds in flight across the barrier)
#define BAR_PREF  asm volatile("s_waitcnt vmcnt(4) lgkmcnt(0)\n\ts_barrier" ::: "memory")
#define BAR_LAST  asm volatile("s_waitcnt vmcnt(0) lgkmcnt(0)\n\ts_barrier" ::: "memory")
#define BAR_PLAIN asm volatile("s_barrier" ::: "memory")

// fp32 -> bf16 round-to-nearest-even
__device__ __forceinline__ u16 f2bf(float f) {
  union { float f; uint32_t u; } v; v.f = f;
  uint32_t u = v.u;
  u += 0x7fffu + ((u >> 16) & 1u);
  return (u16)(u >> 16);
}
__device__ __forceinline__ float bf2f(u16 u) {
  union { uint32_t u; float f; } v; v.u = ((uint32_t)u) << 16; return v.f;
}

// async global->LDS, 16B per lane; lds dest must be wave-uniform (lane i -> lds + i*16B)
__device__ __forceinline__ void gld_lds16(const u16* g, u16* lds) {
  __builtin_amdgcn_global_load_lds(
      (const __attribute__((address_space(1))) uint32_t*)g,
      (__attribute__((address_space(3))) uint32_t*)lds,
      16, 0, 0);
}

// ---------------- cast: x, Wk, Wq, Wv, Wp -> bf16 ----------------
__global__ __launch_bounds__(256) void cast_all(
    const float* __restrict__ x,  const float* __restrict__ wk,
    const float* __restrict__ wq, const float* __restrict__ wv,
    const float* __restrict__ wp,
    u16* __restrict__ xb, u16* __restrict__ wkb, u16* __restrict__ wqb,
    u16* __restrict__ wvb, u16* __restrict__ wpb) {
  const int NX = NM * NC / 4;   // 1048576 float4s
  const int NW = NC * NC / 4;   // 262144 float4s
  int i = blockIdx.x * 256 + threadIdx.x;
  const float* src; u16* dst; int off;
  if (i < NX)            { src = x;  dst = xb;  off = i; }
  else if (i < NX+NW)    { src = wk; dst = wkb; off = i - NX; }
  else if (i < NX+2*NW)  { src = wq; dst = wqb; off = i - NX - NW; }
  else if (i < NX+3*NW)  { src = wv; dst = wvb; off = i - NX - 2*NW; }
  else if (i < NX+4*NW)  { src = wp; dst = wpb; off = i - NX - 3*NW; }
  else return;
  float4v f = ((const float4v*)src)[off];
  short4v o;
  o.x = (short)f2bf(f.x); o.y = (short)f2bf(f.y);
  o.z = (short)f2bf(f.z); o.w = (short)f2bf(f.w);
  ((short4v*)dst)[off] = o;
}

// ---------------- shared 128x128xK GEMM core: C = A * W^T ----------------
__device__ __forceinline__ void gemm_tile(
    const u16* __restrict__ A_tile, const u16* __restrict__ W_tile,
    u16* As, u16* Bs, float4v (&acc)[4][4]) {
  const int tid  = threadIdx.x;
  const int wave = tid >> 6, lane = tid & 63;
  const int quad = lane >> 4, l15 = lane & 15;
  const int wm = wave >> 1, wn = wave & 1;
  const int c8 = lane & 7, r8 = lane >> 3;

#pragma unroll
  for (int i = 0; i < 4; i++)
#pragma unroll
    for (int j = 0; j < 4; j++) acc[i][j] = (float4v){0.f, 0.f, 0.f, 0.f};

  for (int k0 = 0; k0 < NC; k0 += 64) {
#pragma unroll
    for (int i = 0; i < 4; i++) {
      int row = wave * 32 + i * 8 + r8;
      int gc  = c8 ^ (row & 7);
      gld_lds16(A_tile + row * NC + k0 + gc * 8, As + (wave * 32 + i * 8) * 64);
      gld_lds16(W_tile + row * NC + k0 + gc * 8, Bs + (wave * 32 + i * 8) * 64);
    }
    __syncthreads();
#pragma unroll
    for (int kk = 0; kk < 2; kk++) {
      short8 af[4], bf[4];
#pragma unroll
      for (int mt = 0; mt < 4; mt++) {
        int row = wm * 64 + mt * 16 + l15;
        int ch  = (kk * 4 + quad) ^ (row & 7);
        af[mt] = *(const short8*)(As + row * 64 + ch * 8);
      }
#pragma unroll
      for (int nt = 0; nt < 4; nt++) {
        int row = wn * 64 + nt * 16 + l15;
        int ch  = (kk * 4 + quad) ^ (row & 7);
        bf[nt] = *(const short8*)(Bs + row * 64 + ch * 8);
      }
#pragma unroll
      for (int mt = 0; mt < 4; mt++)
#pragma unroll
        for (int nt = 0; nt < 4; nt++)
          acc[mt][nt] = __builtin_amdgcn_mfma_f32_16x16x32_bf16(af[mt], bf[nt], acc[mt][nt], 0, 0, 0);
    }
    __syncthreads();
  }
}

// ---------------- fused QKV projection ----------------
// grid.x: 24 (0-7 -> Q, 8-15 -> K, 16-23 -> V), grid.y: 32 (m tiles)
__global__ __launch_bounds__(256) void qkv_gemm(
    const u16* __restrict__ xb,
    const u16* __restrict__ wqb, const u16* __restrict__ wkb, const u16* __restrict__ wvb,
    const float* __restrict__ bq, const float* __restrict__ bk, const float* __restrict__ bv,
    u16* __restrict__ Q, u16* __restrict__ K, u16* __restrict__ Vb) {
  __shared__ u16 As[128 * 64];
  __shared__ u16 Bs[128 * 64];
  const int nb  = blockIdx.x;
  const int mat = nb >> 3;            // 0=Q 1=K 2=V
  const int n0  = (nb & 7) * 128;
  const int m0  = blockIdx.y * 128;
  const u16*   W    = (mat == 0) ? wqb : (mat == 1) ? wkb : wvb;
  const float* bias = (mat == 0) ? bq  : (mat == 1) ? bk  : bv;
  u16* dst = (mat == 0) ? Q : (mat == 1) ? K : Vb;

  float4v acc[4][4];
  gemm_tile(xb + m0 * NC, W + n0 * NC, As, Bs, acc);

  const int tid = threadIdx.x, wave = tid >> 6, lane = tid & 63;
  const int quad = lane >> 4, l15 = lane & 15;
  const int wm = wave >> 1, wn = wave & 1;
#pragma unroll
  for (int nt = 0; nt < 4; nt++) {
    int col = n0 + wn * 64 + nt * 16 + l15;
    float bval = bias[col];
#pragma unroll
    for (int mt = 0; mt < 4; mt++) {
      int rowb = m0 + wm * 64 + mt * 16 + quad * 4;
#pragma unroll
      for (int r = 0; r < 4; r++)
        dst[(size_t)(rowb + r) * NC + col] = f2bf(acc[mt][nt][r] + bval);
    }
  }
}

// ---------------- V transpose: [4096,1024] -> [B,H,D,T] ----------------
// grid (T/64, B*H), block 256. LDS tile [d=64][t=64] with 16B-chunk XOR swizzle.
__global__ __launch_bounds__(256) void vtrans(const u16* __restrict__ V, u16* __restrict__ Vt) {
  __shared__ u16 tl[64 * 64];
  const int tid = threadIdx.x;
  const int bh = blockIdx.y, b = bh >> 4, h = bh & 15;
  const int t0 = blockIdx.x * 64;
#pragma unroll
  for (int it = 0; it < 2; it++) {
    int idx = it * 256 + tid;        // 0..511
    int row = idx >> 3;              // t within tile
    int ch  = idx & 7;               // d chunk
    short8 vv = *(const short8*)(V + (size_t)(b * NT + t0 + row) * NC + h * ND + ch * 8);
    int xr = (row >> 3) ^ ch;        // swizzle uses d>>3 == ch
    int off = xr * 8 + (row & 7);
#pragma unroll
    for (int j = 0; j < 8; j++) tl[(ch * 8 + j) * 64 + off] = (u16)vv[j];
  }
  __syncthreads();
#pragma unroll
  for (int it = 0; it < 2; it++) {
    int idx = it * 256 + tid;
    int d  = idx >> 3;               // 0..63
    int tc = idx & 7;                // t chunk
    short8 o = *(const short8*)(tl + d * 64 + ((tc ^ ((d >> 3) & 7)) << 3));
    *(short8*)(Vt + (size_t)(bh * ND + d) * NT + t0 + tc * 8) = o;
  }
}

// ---------------- flash attention (causal), split-s + double-buffered ----------------
// grid (48, B*H): x<16: tile=x full range, direct write.
//                 x in [16,32): tile=x, seg0 = chunks 0..15 (partial).
//                 x in [32,48): tile=x-16, seg1 = chunks 16..tile (partial, has diagonal).
__global__ __launch_bounds__(256) void attn(
    const u16* __restrict__ Q, const u16* __restrict__ K,
    const u16* __restrict__ Vt, u16* __restrict__ O,
    u16* __restrict__ Opart, float* __restrict__ Mpart, float* __restrict__ Lpart) {
  __shared__ u16 Kc[2][64 * 64];
  __shared__ u16 Vc[2][64 * 64];
  __shared__ u16 Pl[4][16 * 64];

  const int tid = threadIdx.x, wave = tid >> 6, lane = tid & 63;
  const int quad = lane >> 4, l15 = lane & 15;
  const int c8 = lane & 7, r8 = lane >> 3;
  const int bh = blockIdx.y, b = bh >> 4, h = bh & 15;
  const int x = blockIdx.x;
  int tile, c_lo, c_hi, seg; bool partial;
  if (x < 16)      { tile = x;      c_lo = 0;  c_hi = x;    partial = false; seg = 0; }
  else if (x < 32) { tile = x;      c_lo = 0;  c_hi = 15;   partial = true;  seg = 0; }
  else             { tile = x - 16; c_lo = 16; c_hi = tile; partial = true;  seg = 1; }
  const int qbase = tile * 64 + wave * 16;
  const float scale = 0.125f;  // 1/sqrt(64)

  short8 qf[2];
  {
    const u16* qrow = Q + (size_t)(b * NT + qbase + l15) * NC + h * ND + quad * 8;
    qf[0] = *(const short8*)(qrow);
    qf[1] = *(const short8*)(qrow + 32);
  }

  float m_r[4], l_r[4];
  float4v o_acc[4];
#pragma unroll
  for (int r = 0; r < 4; r++) { m_r[r] = -1e30f; l_r[r] = 0.f; }
#pragma unroll
  for (int dt = 0; dt < 4; dt++) o_acc[dt] = (float4v){0.f, 0.f, 0.f, 0.f};

  auto stage = [&](int ci, int p) {
#pragma unroll
    for (int ii = 0; ii < 2; ii++) {
      int row = wave * 16 + ii * 8 + r8;
      int gc  = c8 ^ (row & 7);
      gld_lds16(K  + (size_t)(b * NT + ci * 64 + row) * NC + h * ND + gc * 8,
                Kc[p] + (wave * 16 + ii * 8) * 64);
      gld_lds16(Vt + (size_t)(bh * ND + row) * NT + ci * 64 + gc * 8,
                Vc[p] + (wave * 16 + ii * 8) * 64);
    }
  };

  stage(c_lo, 0);
  for (int i = c_lo; i <= c_hi; i++) {
    const int p = (i - c_lo) & 1;
    if (i < c_hi) { stage(i + 1, p ^ 1); BAR_PREF; }
    else          { BAR_LAST; }
    const u16* Ks = Kc[p];
    const u16* Vs = Vc[p];

    // S = Q K^T
    float sv[4][4];
    const bool mask_iter = (i == tile);
#pragma unroll
    for (int sub = 0; sub < 4; sub++) {
      float4v a = (float4v){0.f, 0.f, 0.f, 0.f};
#pragma unroll
      for (int kk = 0; kk < 2; kk++) {
        int row = sub * 16 + l15;
        int ch  = (kk * 4 + quad) ^ (row & 7);
        short8 kf = *(const short8*)(Ks + row * 64 + ch * 8);
        a = __builtin_amdgcn_mfma_f32_16x16x32_bf16(qf[kk], kf, a, 0, 0, 0);
      }
#pragma unroll
      for (int r = 0; r < 4; r++) {
        float v = a[r] * scale;
        if (mask_iter) {
          int sg = i * 64 + sub * 16 + l15;
          int qg = qbase + quad * 4 + r;
          if (sg > qg) v = -1e30f;
        }
        sv[sub][r] = v;
      }
    }

    // online softmax
    float mx[4];
#pragma unroll
    for (int r = 0; r < 4; r++)
      mx[r] = fmaxf(fmaxf(sv[0][r], sv[1][r]), fmaxf(sv[2][r], sv[3][r]));
#pragma unroll
    for (int msk = 1; msk < 16; msk <<= 1)
#pragma unroll
      for (int r = 0; r < 4; r++)
        mx[r] = fmaxf(mx[r], __shfl_xor(mx[r], msk));

    float mnew[4], alpha[4], rs[4];
#pragma unroll
    for (int r = 0; r < 4; r++) {
      mnew[r]  = fmaxf(m_r[r], mx[r]);
      alpha[r] = __expf(m_r[r] - mnew[r]);
      rs[r]    = 0.f;
    }

#pragma unroll
    for (int sub = 0; sub < 4; sub++)
#pragma unroll
      for (int r = 0; r < 4; r++) {
        float pv = __expf(sv[sub][r] - mnew[r]);
        rs[r] += pv;
        int row  = quad * 4 + r;
        int colb = sub * 16 + l15;
        int ch   = (colb >> 3) ^ (row & 7);
        Pl[wave][row * 64 + ch * 8 + (colb & 7)] = f2bf(pv);
      }
#pragma unroll
    for (int msk = 1; msk < 16; msk <<= 1)
#pragma unroll
      for (int r = 0; r < 4; r++)
        rs[r] += __shfl_xor(rs[r], msk);
#pragma unroll
    for (int r = 0; r < 4; r++) {
      l_r[r] = l_r[r] * alpha[r] + rs[r];
      m_r[r] = mnew[r];
    }

    asm volatile("s_waitcnt lgkmcnt(0)" ::: "memory");  // own-wave P writes visible

#pragma unroll
    for (int dt = 0; dt < 4; dt++)
#pragma unroll
      for (int r = 0; r < 4; r++)
        o_acc[dt][r] *= alpha[r];
#pragma unroll
    for (int half = 0; half < 2; half++) {
      int chp = (half * 4 + quad) ^ (l15 & 7);
      short8 pf = *(const short8*)(Pl[wave] + l15 * 64 + chp * 8);
#pragma unroll
      for (int dt = 0; dt < 4; dt++) {
        int row = dt * 16 + l15;
        int ch  = (half * 4 + quad) ^ (row & 7);
        short8 vf = *(const short8*)(Vs + row * 64 + ch * 8);
        o_acc[dt] = __builtin_amdgcn_mfma_f32_16x16x32_bf16(pf, vf, o_acc[dt], 0, 0, 0);
      }
    }
    BAR_PLAIN;  // all waves done reading buf p before next iter's DMA overwrites it
  }

  if (!partial) {
#pragma unroll
    for (int dt = 0; dt < 4; dt++)
#pragma unroll
      for (int r = 0; r < 4; r++) {
        int qg = qbase + quad * 4 + r;
        int d  = dt * 16 + l15;
        O[(size_t)(b * NT + qg) * NC + h * ND + d] = f2bf(o_acc[dt][r] / l_r[r]);
      }
  } else {
    int slab = bh * 16 + (tile - 16);
    u16* ob = Opart + ((size_t)seg * 512 + slab) * 4096;
#pragma unroll
    for (int dt = 0; dt < 4; dt++)
#pragma unroll
      for (int r = 0; r < 4; r++) {
        int row = wave * 16 + quad * 4 + r;
        int d   = dt * 16 + l15;
        ob[row * 64 + d] = f2bf(o_acc[dt][r]);   // unnormalized partial
      }
    if (l15 == 0) {
#pragma unroll
      for (int r = 0; r < 4; r++) {
        int row = wave * 16 + quad * 4 + r;
        Mpart[(seg * 512 + slab) * 64 + row] = m_r[r];
        Lpart[(seg * 512 + slab) * 64 + row] = l_r[r];
      }
    }
  }
}

// ---------------- combine split-s partials ----------------
__global__ __launch_bounds__(256) void combine(
    const u16* __restrict__ Opart, const float* __restrict__ Mp,
    const float* __restrict__ Lp, u16* __restrict__ O) {
  int idx  = blockIdx.x * 256 + threadIdx.x;   // 0..4M-1
  int slab = idx >> 12;
  int rem  = idx & 4095;
  int row  = rem >> 6, d = rem & 63;
  float m0 = Mp[slab * 64 + row], m1 = Mp[(512 + slab) * 64 + row];
  float l0 = Lp[slab * 64 + row], l1 = Lp[(512 + slab) * 64 + row];
  float m  = fmaxf(m0, m1);
  float w0 = __expf(m0 - m), w1 = __expf(m1 - m);
  float o0 = bf2f(Opart[(size_t)slab * 4096 + rem]);
  float o1 = bf2f(Opart[(size_t)(512 + slab) * 4096 + rem]);
  float o  = (w0 * o0 + w1 * o1) / (w0 * l0 + w1 * l1);
  int bh = slab >> 4, tile = 16 + (slab & 15);
  int b = bh >> 4, h = bh & 15;
  int t = tile * 64 + row;
  O[(size_t)(b * NT + t) * NC + h * ND + d] = f2bf(o);
}

// ---------------- output projection ----------------
__global__ __launch_bounds__(256) void out_gemm(
    const u16* __restrict__ Ob, const u16* __restrict__ wpb,
    const float* __restrict__ bp, float* __restrict__ out) {
  __shared__ u16 As[128 * 64];
  __shared__ u16 Bs[128 * 64];
  const int n0 = blockIdx.x * 128;
  const int m0 = blockIdx.y * 128;
  float4v acc[4][4];
  gemm_tile(Ob + m0 * NC, wpb + n0 * NC, As, Bs, acc);

  const int tid = threadIdx.x, wave = tid >> 6, lane = tid & 63;
  const int quad = lane >> 4, l15 = lane & 15;
  const int wm = wave >> 1, wn = wave & 1;
#pragma unroll
  for (int nt = 0; nt < 4; nt++) {
    int col = n0 + wn * 64 + nt * 16 + l15;
    float bval = bp[col];
#pragma unroll
    for (int mt = 0; mt < 4; mt++) {
      int rowb = m0 + wm * 64 + mt * 16 + quad * 4;
#pragma unroll
      for (int r = 0; r < 4; r++)
        out[(rowb + r) * NC + col] = acc[mt][nt][r] + bval;
    }
  }
}

extern "C" void kernel_launch(void* const* d_in, const int* in_sizes, int n_in,
                              void* d_out, int out_size, void* d_ws, size_t ws_size,
                              hipStream_t stream) {
  // setup_inputs order: x, Wk, bk, Wq, bq, Wv, bv, Wp, bp
  const float* x  = (const float*)d_in[0];
  const float* Wk = (const float*)d_in[1];
  const float* bk = (const float*)d_in[2];
  const float* Wq = (const float*)d_in[3];
  const float* bq = (const float*)d_in[4];
  const float* Wv = (const float*)d_in[5];
  const float* bv = (const float*)d_in[6];
  const float* Wp = (const float*)d_in[7];
  const float* bp = (const float*)d_in[8];
  float* out = (float*)d_out;

  uint8_t* ws = (uint8_t*)d_ws;
  const size_t MB = 1u << 20;
  // phase 1 (cast+qkv):  xb[0,8) wkb[8,10) wqb[10,12) wvb[12,14) wpb[14,16)
  // phase 2 (attn):      Opart[0,8) Mp/Lp[8,8.5)  (xb/wkb dead)
  // Vb lives at [40,48) (written by qkv, read by vtrans, then overwritten by Ob)
  u16* xb    = (u16*)(ws + 0 * MB);
  u16* wkb   = (u16*)(ws + 8 * MB);
  u16* wqb   = (u16*)(ws + 10 * MB);
  u16* wvb   = (u16*)(ws + 12 * MB);
  u16* wpb   = (u16*)(ws + 14 * MB);
  u16* Qb    = (u16*)(ws + 16 * MB);
  u16* Kb    = (u16*)(ws + 24 * MB);
  u16* Vtb   = (u16*)(ws + 32 * MB);   // [B,H,D,T]
  u16* Vb    = (u16*)(ws + 40 * MB);   // row-major V (transient)
  u16* Ob    = (u16*)(ws + 40 * MB);   // attention output, overwrites Vb
  u16* Opart = (u16*)(ws + 0 * MB);    // reuses xb region
  float* Mpart = (float*)(ws + 8 * MB);               // 256 KB
  float* Lpart = (float*)(ws + 8 * MB + 256 * 1024);  // 256 KB

  cast_all<<<8192, 256, 0, stream>>>(x, Wk, Wq, Wv, Wp, xb, wkb, wqb, wvb, wpb);
  qkv_gemm<<<dim3(24, 32), 256, 0, stream>>>(xb, wqb, wkb, wvb, bq, bk, bv, Qb, Kb, Vb);
  vtrans<<<dim3(32, 32), 256, 0, stream>>>(Vb, Vtb);
  attn<<<dim3(48, 32), 256, 0, stream>>>(Qb, Kb, Vtb, Ob, Opart, Mpart, Lpart);
  combine<<<16384, 256, 0, stream>>>(Opart, Mpart, Lpart, Ob);
  out_gemm<<<dim3(8, 32), 256, 0, stream>>>(Ob, wpb, bp, out);
}